// Round 1
// baseline (166.662 us; speedup 1.0000x reference)
//
#include <hip/hip_runtime.h>

// GridMask: out[n,c,s,h,w] = x * ((rowhit(n,s,h) | colhit(n,s,w)) ? 1 : 0)
// rowhit(h) = ((h + OFF_H - st_h[n,s] mod d) mod d) < ceil(d/2)
// colhit(w) = ((w + OFF_W - st_w[n,s] mod d) mod d) < ceil(d/2)
// N=8 C=3 S=16 H=W=512, OFF_H=OFF_W=106 (HH=725)

#define NN 8
#define CC 3
#define SS 16
#define HH_ 512
#define WW 512
#define OFFH 106
#define OFFW 106

// Pass 1: carve the tiny per-(n,s) hit vectors into d_ws.
// rowhit: [N*S][512] bytes at ws+0 ; colhit: [N*S][512] bytes at ws+65536.
__global__ void gridmask_mask_kernel(const int* __restrict__ d,
                                     const int* __restrict__ st_h,
                                     const int* __restrict__ st_w,
                                     unsigned char* __restrict__ rowhit,
                                     unsigned char* __restrict__ colhit) {
    const int ns = blockIdx.x;            // 0..127
    const int n = ns >> 4, s = ns & 15;
    const int dd = d[n];
    const int l  = (dd + 1) >> 1;         // ceil(d * 0.5)
    const int sth = st_h[n * SS + s] % dd;
    const int stw = st_w[n * SS + s] % dd;
    const int t = threadIdx.x;            // 0..511 (H == W == 512)

    int r = (t + OFFH - sth) % dd; if (r < 0) r += dd;   // python-mod
    rowhit[ns * HH_ + t] = (r < l) ? 1u : 0u;

    int c = (t + OFFW - stw) % dd; if (c < 0) c += dd;
    colhit[ns * WW + t] = (c < l) ? 1u : 0u;
}

// Pass 2: stream x -> out with float4, mask from cached hit vectors.
__global__ void gridmask_apply_kernel(const float4* __restrict__ x,
                                      const unsigned char* __restrict__ rowhit,
                                      const unsigned int* __restrict__ colhit4,
                                      float4* __restrict__ out,
                                      int total4) {
    const int stride = gridDim.x * blockDim.x;
    for (int i = blockIdx.x * blockDim.x + threadIdx.x; i < total4; i += stride) {
        // i -> (n, c, s, h, w4); W/4 = 128, H = 512, S = 16, C = 3
        const int w4  = i & 127;
        const int h   = (i >> 7) & 511;
        const int scn = i >> 16;
        const int s   = scn & 15;
        const int cn  = scn >> 4;       // c + 3*... no: layout is n,c,s -> cn = n*C + c
        const int n   = cn / 3;         // cn in [0, 24)
        const int ns  = n * SS + s;

        const unsigned int row = rowhit[ns * HH_ + h];
        const unsigned int col = colhit4[ns * (WW / 4) + w4]; // 4 packed bytes

        const float4 v = x[i];
        float4 o;
        o.x = (row | (col & 0x000000ffu)) ? v.x : 0.0f;
        o.y = (row | (col & 0x0000ff00u)) ? v.y : 0.0f;
        o.z = (row | (col & 0x00ff0000u)) ? v.z : 0.0f;
        o.w = (row | (col & 0xff000000u)) ? v.w : 0.0f;
        out[i] = o;
    }
}

extern "C" void kernel_launch(void* const* d_in, const int* in_sizes, int n_in,
                              void* d_out, int out_size, void* d_ws, size_t ws_size,
                              hipStream_t stream) {
    const float* x   = (const float*)d_in[0];
    const int* d     = (const int*)d_in[1];
    const int* st_h  = (const int*)d_in[2];
    const int* st_w  = (const int*)d_in[3];
    float* out       = (float*)d_out;

    unsigned char* rowhit = (unsigned char*)d_ws;
    unsigned char* colhit = rowhit + NN * SS * HH_;   // +65536 bytes

    gridmask_mask_kernel<<<NN * SS, 512, 0, stream>>>(d, st_h, st_w, rowhit, colhit);

    const int total4 = NN * CC * SS * HH_ * WW / 4;   // 25,165,824
    gridmask_apply_kernel<<<2048, 256, 0, stream>>>(
        (const float4*)x, rowhit, (const unsigned int*)colhit, (float4*)out, total4);
}